// Round 1
// baseline (284.807 us; speedup 1.0000x reference)
//
#include <hip/hip_runtime.h>

// Problem constants
// B=4, H=W=64, D=256, N=8, K=V=32, H2=W2=32, HW=4096, M=1024 pooled/batch.

typedef __bf16 bf16x8 __attribute__((ext_vector_type(8)));
typedef float  f32x4  __attribute__((ext_vector_type(4)));

__device__ __forceinline__ unsigned short f2bf(float f) {
    // round-to-nearest-even fp32 -> bf16 (values are finite here)
    unsigned u = __builtin_bit_cast(unsigned, f);
    u = (u + 0x7fffu + ((u >> 16) & 1u)) >> 16;
    return (unsigned short)u;
}

// ---------------- P0a: 2x2 maxpool (NHWC) -> pooled fp32 [4096][256] --------
__global__ void pool_kernel(const float* __restrict__ blob, float* __restrict__ pooled) {
    int idx = blockIdx.x * 256 + threadIdx.x;     // 1,048,576 exact
    int d = idx & 255;
    int m = idx >> 8;                             // 0..4095  (b*1024 + y*32 + x)
    int x = m & 31, y = (m >> 5) & 31, b = m >> 10;
    const float* p = blob + ((((b * 64 + 2 * y) * 64) + 2 * x) << 8) + d;
    float v0 = p[0], v1 = p[256], v2 = p[64 * 256], v3 = p[64 * 256 + 256];
    pooled[idx] = fmaxf(fmaxf(v0, v1), fmaxf(v2, v3));
}

// ---------------- P0b: weights -> bf16 transposed Wt[mat][o][d] -------------
__global__ void wt_kernel(const float* __restrict__ wq, const float* __restrict__ wk,
                          const float* __restrict__ wv, unsigned short* __restrict__ wt) {
    int idx = blockIdx.x * 256 + threadIdx.x;     // 196,608 exact
    int mat = idx >> 16;
    int r = idx & 65535;
    int d = r >> 8, o = r & 255;                  // coalesced read along o
    const float* w = (mat == 0) ? wq : (mat == 1 ? wk : wv);
    wt[(mat << 16) + o * 256 + d] = f2bf(w[d * 256 + o]);
}

// ---------------- P1: projection GEMM  C[rows][256] = A[rows][256] @ W ------
// JOB 0: Q (pooled src, scale 1/sqrt(32), dst [bn][m][32])
// JOB 1: K (blob src,                  dst [bn][i][32])
// JOB 2: V (blob src, swish,           dst [bn][v][4096]  == V^T)
template <int JOB>
__global__ __launch_bounds__(256) void proj_kernel(
    const float* __restrict__ src, const unsigned short* __restrict__ wt,
    const float* __restrict__ bias, unsigned short* __restrict__ dst) {
    const int lane = threadIdx.x & 63;
    const int wid  = threadIdx.x >> 6;
    const int quad = lane >> 4;
    const int l16  = lane & 15;
    const int rowbase = blockIdx.x * 64 + wid * 16;

    f32x4 acc[16];
#pragma unroll
    for (int i = 0; i < 16; ++i) acc[i] = (f32x4){0.f, 0.f, 0.f, 0.f};

    const float* arow = src + (rowbase + l16) * 256;
#pragma unroll
    for (int kc = 0; kc < 8; ++kc) {
        const float4 fa = *(const float4*)(arow + kc * 32 + quad * 8);
        const float4 fb = *(const float4*)(arow + kc * 32 + quad * 8 + 4);
        union { unsigned short us[8]; bf16x8 v; } cv;
        cv.us[0] = f2bf(fa.x); cv.us[1] = f2bf(fa.y); cv.us[2] = f2bf(fa.z); cv.us[3] = f2bf(fa.w);
        cv.us[4] = f2bf(fb.x); cv.us[5] = f2bf(fb.y); cv.us[6] = f2bf(fb.z); cv.us[7] = f2bf(fb.w);
#pragma unroll
        for (int nt = 0; nt < 16; ++nt) {
            const bf16x8 bfr = *(const bf16x8*)(wt + (nt * 16 + l16) * 256 + kc * 32 + quad * 8);
            acc[nt] = __builtin_amdgcn_mfma_f32_16x16x32_bf16(cv.v, bfr, acc[nt], 0, 0, 0);
        }
    }

#pragma unroll
    for (int nt = 0; nt < 16; ++nt) {
        const int o = nt * 16 + l16;              // output column 0..255
        const float bs = bias[o];
        const int n = o >> 5, kk = o & 31;
#pragma unroll
        for (int r = 0; r < 4; ++r) {
            const int grow = rowbase + quad * 4 + r;   // global row (C layout)
            float x = acc[nt][r] + bs;
            if (JOB == 0) {
                x *= 0.17677669529663687f;        // 1/sqrt(32)
                const int b = grow >> 10, m = grow & 1023;
                dst[(((b * 8 + n) * 1024 + m) << 5) + kk] = f2bf(x);
            } else if (JOB == 1) {
                const int b = grow >> 12, i = grow & 4095;
                dst[(((b * 8 + n) * 4096 + i) << 5) + kk] = f2bf(x);
            } else {
                const float sg = 1.0f / (1.0f + __expf(-x));
                x = x * sg;                       // swish
                const int b = grow >> 12, i = grow & 4095;
                dst[(((b * 8 + n) * 32 + kk) << 12) + i] = f2bf(x);
            }
        }
    }
}

// ---------------- P2: flash attention over L=4096 keys ----------------------
// grid: 512 blocks = (bn 0..31) x (qt 0..15); block = 4 waves x 16 q-rows.
__global__ __launch_bounds__(256) void attn_kernel(
    const unsigned short* __restrict__ qb,   // [32][1024][32] bf16
    const unsigned short* __restrict__ kb,   // [32][4096][32] bf16
    const unsigned short* __restrict__ vt,   // [32][32][4096] bf16 (V^T)
    float* __restrict__ out) {               // [4][1024][256] fp32
    // per-wave private P tile, double buffered; row padded 64->72 ushorts
    __shared__ __align__(16) unsigned short plds[4][2][16][72];

    const int lane = threadIdx.x & 63;
    const int wid  = threadIdx.x >> 6;
    const int quad = lane >> 4;
    const int l16  = lane & 15;
    const int bn = blockIdx.x >> 4;          // b*8+n
    const int qt = blockIdx.x & 15;
    const int b = bn >> 3, n = bn & 7;
    const int m0 = qt * 64 + wid * 16;

    const bf16x8 qf = *(const bf16x8*)(qb + ((bn * 1024 + m0 + l16) << 5) + quad * 8);
    const unsigned short* kbase = kb + ((size_t)bn << 17);   // bn*4096*32
    const unsigned short* vbase = vt + ((size_t)bn << 17);   // bn*32*4096

    f32x4 o0 = (f32x4){0.f, 0.f, 0.f, 0.f};
    f32x4 o1 = (f32x4){0.f, 0.f, 0.f, 0.f};
    float mrow[4], lrow[4];
#pragma unroll
    for (int r = 0; r < 4; ++r) { mrow[r] = -__builtin_inff(); lrow[r] = 0.f; }

    for (int i0 = 0; i0 < 4096; i0 += 64) {
        const int buf = (i0 >> 6) & 1;
        // --- scores S[16 m][64 i] : 4 MFMAs, k=32 fully contracted ---
        f32x4 s[4];
#pragma unroll
        for (int t = 0; t < 4; ++t) {
            const bf16x8 kf = *(const bf16x8*)(kbase + ((i0 + t * 16 + l16) << 5) + quad * 8);
            s[t] = __builtin_amdgcn_mfma_f32_16x16x32_bf16(qf, kf, (f32x4){0.f, 0.f, 0.f, 0.f}, 0, 0, 0);
        }
        // --- online softmax state update (row = quad*4 + r) ---
        float mnew[4], alpha[4];
#pragma unroll
        for (int r = 0; r < 4; ++r) {
            float tm = fmaxf(fmaxf(s[0][r], s[1][r]), fmaxf(s[2][r], s[3][r]));
            tm = fmaxf(tm, __shfl_xor(tm, 1));
            tm = fmaxf(tm, __shfl_xor(tm, 2));
            tm = fmaxf(tm, __shfl_xor(tm, 4));
            tm = fmaxf(tm, __shfl_xor(tm, 8));
            mnew[r] = fmaxf(mrow[r], tm);
            alpha[r] = __expf(mrow[r] - mnew[r]);
            mrow[r] = mnew[r];
        }
#pragma unroll
        for (int r = 0; r < 4; ++r) {
            float rs = 0.f;
#pragma unroll
            for (int t = 0; t < 4; ++t) {
                const float p = __expf(s[t][r] - mnew[r]);
                rs += p;
                plds[wid][buf][quad * 4 + r][t * 16 + l16] = f2bf(p);
            }
            rs += __shfl_xor(rs, 1);
            rs += __shfl_xor(rs, 2);
            rs += __shfl_xor(rs, 4);
            rs += __shfl_xor(rs, 8);
            lrow[r] = lrow[r] * alpha[r] + rs;
            o0[r] *= alpha[r];
            o1[r] *= alpha[r];
        }
        // ensure this wave's LDS writes complete before cross-lane reads
        asm volatile("s_waitcnt lgkmcnt(0)" ::: "memory");
        // --- P in A-operand layout; V^T B-fragments; 4 PV MFMAs ---
        const bf16x8 a0 = *(const bf16x8*)&plds[wid][buf][l16][quad * 8];
        const bf16x8 a1 = *(const bf16x8*)&plds[wid][buf][l16][32 + quad * 8];
        const bf16x8 v00 = *(const bf16x8*)(vbase + (l16 << 12) + i0 + quad * 8);
        const bf16x8 v01 = *(const bf16x8*)(vbase + (l16 << 12) + i0 + 32 + quad * 8);
        const bf16x8 v10 = *(const bf16x8*)(vbase + ((16 + l16) << 12) + i0 + quad * 8);
        const bf16x8 v11 = *(const bf16x8*)(vbase + ((16 + l16) << 12) + i0 + 32 + quad * 8);
        o0 = __builtin_amdgcn_mfma_f32_16x16x32_bf16(a0, v00, o0, 0, 0, 0);
        o0 = __builtin_amdgcn_mfma_f32_16x16x32_bf16(a1, v01, o0, 0, 0, 0);
        o1 = __builtin_amdgcn_mfma_f32_16x16x32_bf16(a0, v10, o1, 0, 0, 0);
        o1 = __builtin_amdgcn_mfma_f32_16x16x32_bf16(a1, v11, o1, 0, 0, 0);
    }

    // --- epilogue: normalize and store fp32 ---
#pragma unroll
    for (int r = 0; r < 4; ++r) {
        const float inv = 1.0f / lrow[r];
        const int row = m0 + quad * 4 + r;               // query row within b
        float* op = out + (((b * 1024 + row) << 8)) + n * 32;
        op[l16] = o0[r] * inv;
        op[16 + l16] = o1[r] * inv;
    }
}

// ---------------- launch -----------------------------------------------------
extern "C" void kernel_launch(void* const* d_in, const int* in_sizes, int n_in,
                              void* d_out, int out_size, void* d_ws, size_t ws_size,
                              hipStream_t stream) {
    const float* blob = (const float*)d_in[0];
    const float* wq = (const float*)d_in[1];
    const float* bq = (const float*)d_in[2];
    const float* wk = (const float*)d_in[3];
    const float* bk = (const float*)d_in[4];
    const float* wv = (const float*)d_in[5];
    const float* bv = (const float*)d_in[6];
    float* out = (float*)d_out;

    char* ws = (char*)d_ws;
    float*          pooled = (float*)(ws);                       // 4,194,304 B
    unsigned short* wt     = (unsigned short*)(ws + 4194304);    //   393,216 B
    unsigned short* qbf    = (unsigned short*)(ws + 4587520);    // 2,097,152 B
    unsigned short* kbf    = (unsigned short*)(ws + 6684672);    // 8,388,608 B
    unsigned short* vtb    = (unsigned short*)(ws + 15073280);   // 8,388,608 B

    pool_kernel<<<4096, 256, 0, stream>>>(blob, pooled);
    wt_kernel<<<768, 256, 0, stream>>>(wq, wk, wv, wt);
    proj_kernel<0><<<64, 256, 0, stream>>>(pooled, wt, bq, qbf);
    proj_kernel<1><<<256, 256, 0, stream>>>(blob, wt + 65536, bk, kbf);
    proj_kernel<2><<<256, 256, 0, stream>>>(blob, wt + 131072, bv, vtb);
    attn_kernel<<<512, 256, 0, stream>>>(qbf, kbf, vtb, out);
}

// Round 3
// 228.373 us; speedup vs baseline: 1.2471x; 1.2471x over previous
//
#include <hip/hip_runtime.h>

// B=4, H=W=64, D=256, N=8, K=V=32, H2=W2=32, HW=4096, M=1024 pooled/batch.

typedef _Float16 f16x8 __attribute__((ext_vector_type(8)));
typedef _Float16 f16x4 __attribute__((ext_vector_type(4)));
typedef float    f32x4 __attribute__((ext_vector_type(4)));

#define F16(x) static_cast<_Float16>(x)

// ---------------- prep: weights -> f16 transposed Wt[mat][o][d] -------------
__global__ void prep_kernel(const float* __restrict__ wq, const float* __restrict__ wk,
                            const float* __restrict__ wv, _Float16* __restrict__ wt) {
    int idx = blockIdx.x * 256 + threadIdx.x;     // 196,608 exact
    int mat = idx >> 16;
    int r = idx & 65535;
    int d = r >> 8, o = r & 255;                  // coalesced read along o
    const float* w = (mat == 0) ? wq : (mat == 1 ? wk : wv);
    wt[(mat << 16) + o * 256 + d] = (_Float16)w[d * 256 + o];
}

// ---------------- proj: all three 1x1-conv GEMMs in one launch --------------
// job 0: Q (fused 2x2 maxpool on A, scale 1/sqrt(32), dst [bn][m][32])  256 blocks
// job 1: K (dst [bn][i][32])                                           1024 blocks
// job 2: V (swish, dst [bn][v][4096] == V^T)                           1024 blocks
// block = 16 rows x 256 cols; 4 waves, each 16 rows x 64 cols.
__global__ __launch_bounds__(256) void proj_kernel(
    const float* __restrict__ blob, const _Float16* __restrict__ wt,
    const float* __restrict__ bq, const float* __restrict__ bk, const float* __restrict__ bv,
    _Float16* __restrict__ qo, _Float16* __restrict__ ko, _Float16* __restrict__ vo) {
    const int lane = threadIdx.x & 63, wid = threadIdx.x >> 6;
    const int quad = lane >> 4, l16 = lane & 15;
    int jb = blockIdx.x;
    int job, rowblk;
    if (jb < 256)       { job = 0; rowblk = jb; }
    else if (jb < 1280) { job = 1; rowblk = jb - 256; }
    else                { job = 2; rowblk = jb - 1280; }
    const int rowbase = rowblk * 16;
    const int colbase = wid * 64;
    const _Float16* wmat = wt + ((size_t)job << 16);
    const float* bias = (job == 0) ? bq : (job == 1 ? bk : bv);

    f32x4 acc[4];
#pragma unroll
    for (int i = 0; i < 4; ++i) acc[i] = (f32x4){0.f, 0.f, 0.f, 0.f};

    const float* a0;
    if (job == 0) {
        const int m = rowbase + l16;             // pooled row 0..4095
        const int bb = m >> 10, y = (m >> 5) & 31, x = m & 31;
        a0 = blob + (((bb * 64 + 2 * y) * 64) + 2 * x) * 256;
    } else {
        a0 = blob + (size_t)(rowbase + l16) * 256;
    }

#pragma unroll
    for (int kc = 0; kc < 8; ++kc) {
        const float* ap = a0 + kc * 32 + quad * 8;
        float va[8];
        if (job == 0) {
            float4 p0 = *(const float4*)(ap);
            float4 p1 = *(const float4*)(ap + 4);
            float4 q0 = *(const float4*)(ap + 256);
            float4 q1 = *(const float4*)(ap + 260);
            float4 r0 = *(const float4*)(ap + 16384);
            float4 r1 = *(const float4*)(ap + 16388);
            float4 s0 = *(const float4*)(ap + 16640);
            float4 s1 = *(const float4*)(ap + 16644);
            va[0] = fmaxf(fmaxf(p0.x, q0.x), fmaxf(r0.x, s0.x));
            va[1] = fmaxf(fmaxf(p0.y, q0.y), fmaxf(r0.y, s0.y));
            va[2] = fmaxf(fmaxf(p0.z, q0.z), fmaxf(r0.z, s0.z));
            va[3] = fmaxf(fmaxf(p0.w, q0.w), fmaxf(r0.w, s0.w));
            va[4] = fmaxf(fmaxf(p1.x, q1.x), fmaxf(r1.x, s1.x));
            va[5] = fmaxf(fmaxf(p1.y, q1.y), fmaxf(r1.y, s1.y));
            va[6] = fmaxf(fmaxf(p1.z, q1.z), fmaxf(r1.z, s1.z));
            va[7] = fmaxf(fmaxf(p1.w, q1.w), fmaxf(r1.w, s1.w));
        } else {
            float4 f0 = *(const float4*)(ap);
            float4 f1 = *(const float4*)(ap + 4);
            va[0] = f0.x; va[1] = f0.y; va[2] = f0.z; va[3] = f0.w;
            va[4] = f1.x; va[5] = f1.y; va[6] = f1.z; va[7] = f1.w;
        }
        auto c0 = __builtin_amdgcn_cvt_pkrtz(va[0], va[1]);
        auto c1 = __builtin_amdgcn_cvt_pkrtz(va[2], va[3]);
        auto c2 = __builtin_amdgcn_cvt_pkrtz(va[4], va[5]);
        auto c3 = __builtin_amdgcn_cvt_pkrtz(va[6], va[7]);
        f16x8 af = {F16(c0[0]), F16(c0[1]), F16(c1[0]), F16(c1[1]),
                    F16(c2[0]), F16(c2[1]), F16(c3[0]), F16(c3[1])};
#pragma unroll
        for (int nt = 0; nt < 4; ++nt) {
            const f16x8 bf = *(const f16x8*)(wmat + (colbase + nt * 16 + l16) * 256 + kc * 32 + quad * 8);
            acc[nt] = __builtin_amdgcn_mfma_f32_16x16x32_f16(af, bf, acc[nt], 0, 0, 0);
        }
    }

#pragma unroll
    for (int nt = 0; nt < 4; ++nt) {
        const int o = colbase + nt * 16 + l16;
        const float bs = bias[o];
        const int nh = o >> 5, kk = o & 31;
        if (job == 0) {
#pragma unroll
            for (int r = 0; r < 4; ++r) {
                const int grow = rowbase + quad * 4 + r;
                const float x = (acc[nt][r] + bs) * 0.17677669529663687f;
                const int bb = grow >> 10, mm = grow & 1023;
                qo[(((bb * 8 + nh) * 1024 + mm) << 5) + kk] = (_Float16)x;
            }
        } else if (job == 1) {
#pragma unroll
            for (int r = 0; r < 4; ++r) {
                const int grow = rowbase + quad * 4 + r;
                const float x = acc[nt][r] + bs;
                const int bb = grow >> 12, ii = grow & 4095;
                ko[(((bb * 8 + nh) * 4096 + ii) << 5) + kk] = (_Float16)x;
            }
        } else {
            const int grow0 = rowbase + quad * 4;
            const int bb = grow0 >> 12, i0 = grow0 & 4095;
            f16x4 pv;
#pragma unroll
            for (int r = 0; r < 4; ++r) {
                float x = acc[nt][r] + bs;
                const float sg = 1.0f / (1.0f + __expf(-x));
                pv[r] = (_Float16)(x * sg);
            }
            *(f16x4*)(vo + (((size_t)(bb * 8 + nh) * 32 + kk) << 12) + i0) = pv;
        }
    }
}

// ---------------- attn: no-max softmax, transposed scores, no main-loop LDS -
// grid: 1024 blocks = (bn 0..31) x (mblk 0..31); block = 8 waves (512 thr).
// Block covers 32 q-rows; wave w handles keys [w*512, (w+1)*512).
__global__ __launch_bounds__(512) void attn_kernel(
    const _Float16* __restrict__ qb,   // [32][1024][32]
    const _Float16* __restrict__ kb,   // [32][4096][32]
    const _Float16* __restrict__ vt,   // [32][32][4096]  (V^T)
    float* __restrict__ out) {         // [4][1024][256]
    __shared__ float cbuf[32][33];     // [v][m] numerator accumulate (+1 pad)
    __shared__ float csum[32];         // denominator per m

    const int tid = threadIdx.x;
    const int lane = tid & 63, wid = tid >> 6;
    const int quad = lane >> 4, l16 = lane & 15;
    const int bn = blockIdx.x >> 5, mblk = blockIdx.x & 31;
    const int b = bn >> 3, n = bn & 7;
    const int m0 = mblk * 32;

    for (int i = tid; i < 32 * 33; i += 512) ((float*)cbuf)[i] = 0.f;
    if (tid < 32) csum[tid] = 0.f;
    __syncthreads();

    const f16x8 qf0 = *(const f16x8*)(qb + (((bn << 10) + m0 + l16) << 5) + quad * 8);
    const f16x8 qf1 = *(const f16x8*)(qb + (((bn << 10) + m0 + 16 + l16) << 5) + quad * 8);
    const _Float16* kptr = kb + ((size_t)bn << 17) + ((wid << 9) + l16) * 32 + quad * 8;
    const _Float16* vp0  = vt + ((size_t)bn << 17) + l16 * 4096 + (wid << 9) + quad * 4;
    const _Float16* vp1  = vp0 + (16 << 12);

    f32x4 a00 = (f32x4){0.f,0.f,0.f,0.f}, a01 = a00, a10 = a00, a11 = a00;
    float ps0 = 0.f, ps1 = 0.f;

    for (int it = 0; it < 32; ++it) {
        const f16x8 kf  = *(const f16x8*)kptr;  kptr += 16 * 32;
        const f16x4 va0 = *(const f16x4*)vp0;   vp0 += 16;
        const f16x4 va1 = *(const f16x4*)vp1;   vp1 += 16;
        // S^T tiles: C[i=quad*4+r][m=l16]
        f32x4 s0 = __builtin_amdgcn_mfma_f32_16x16x32_f16(kf, qf0, (f32x4){0.f,0.f,0.f,0.f}, 0, 0, 0);
        f32x4 s1 = __builtin_amdgcn_mfma_f32_16x16x32_f16(kf, qf1, (f32x4){0.f,0.f,0.f,0.f}, 0, 0, 0);
        const float p0 = __expf(s0[0]), p1 = __expf(s0[1]), p2 = __expf(s0[2]), p3 = __expf(s0[3]);
        const float u0 = __expf(s1[0]), u1 = __expf(s1[1]), u2 = __expf(s1[2]), u3 = __expf(s1[3]);
        ps0 += (p0 + p1) + (p2 + p3);
        ps1 += (u0 + u1) + (u2 + u3);
        auto e0 = __builtin_amdgcn_cvt_pkrtz(p0, p1);
        auto e1 = __builtin_amdgcn_cvt_pkrtz(p2, p3);
        auto e2 = __builtin_amdgcn_cvt_pkrtz(u0, u1);
        auto e3 = __builtin_amdgcn_cvt_pkrtz(u2, u3);
        const f16x4 pb0 = {F16(e0[0]), F16(e0[1]), F16(e1[0]), F16(e1[1])};  // B[k=quad*4+j][m=l16]
        const f16x4 pb1 = {F16(e2[0]), F16(e2[1]), F16(e3[0]), F16(e3[1])};
        // out^T[v][m] += V^T-frag . P^T-frag  (k=16 contraction over keys)
        a00 = __builtin_amdgcn_mfma_f32_16x16x16f16(va0, pb0, a00, 0, 0, 0);
        a10 = __builtin_amdgcn_mfma_f32_16x16x16f16(va1, pb0, a10, 0, 0, 0);
        a01 = __builtin_amdgcn_mfma_f32_16x16x16f16(va0, pb1, a01, 0, 0, 0);
        a11 = __builtin_amdgcn_mfma_f32_16x16x16f16(va1, pb1, a11, 0, 0, 0);
    }

    // denominator: reduce partial sums across the 4 quads
    ps0 += __shfl_xor(ps0, 16); ps0 += __shfl_xor(ps0, 32);
    ps1 += __shfl_xor(ps1, 16); ps1 += __shfl_xor(ps1, 32);

    // block combine: LDS atomic accumulate (8 waves, disjoint key chunks)
#pragma unroll
    for (int r = 0; r < 4; ++r) {
        atomicAdd(&cbuf[quad * 4 + r][l16],       a00[r]);
        atomicAdd(&cbuf[16 + quad * 4 + r][l16],  a10[r]);
        atomicAdd(&cbuf[quad * 4 + r][16 + l16],  a01[r]);
        atomicAdd(&cbuf[16 + quad * 4 + r][16 + l16], a11[r]);
    }
    if (lane < 16) {
        atomicAdd(&csum[l16], ps0);
        atomicAdd(&csum[16 + l16], ps1);
    }
    __syncthreads();

    // normalize + store: 1024 outputs, 512 threads x 2
    {
        int m = tid >> 5;
        const int v = tid & 31;
        float inv = 1.0f / csum[m];
        out[(((b << 10) + m0 + m) << 8) + n * 32 + v] = cbuf[v][m] * inv;
        m += 16;
        inv = 1.0f / csum[m];
        out[(((b << 10) + m0 + m) << 8) + n * 32 + v] = cbuf[v][m] * inv;
    }
}

// ---------------- launch -----------------------------------------------------
extern "C" void kernel_launch(void* const* d_in, const int* in_sizes, int n_in,
                              void* d_out, int out_size, void* d_ws, size_t ws_size,
                              hipStream_t stream) {
    const float* blob = (const float*)d_in[0];
    const float* wq = (const float*)d_in[1];
    const float* bq = (const float*)d_in[2];
    const float* wk = (const float*)d_in[3];
    const float* bk = (const float*)d_in[4];
    const float* wv = (const float*)d_in[5];
    const float* bv = (const float*)d_in[6];
    float* out = (float*)d_out;

    char* ws = (char*)d_ws;
    _Float16* wt = (_Float16*)(ws);                    //   393,216 B
    _Float16* qo = (_Float16*)(ws + 393216);           // 2,097,152 B
    _Float16* ko = (_Float16*)(ws + 2490368);          // 8,388,608 B
    _Float16* vo = (_Float16*)(ws + 10878976);         // 8,388,608 B

    prep_kernel<<<768, 256, 0, stream>>>(wq, wk, wv, wt);
    proj_kernel<<<2304, 256, 0, stream>>>(blob, wt, bq, bk, bv, qo, ko, vo);
    attn_kernel<<<1024, 512, 0, stream>>>(qo, ko, vo, out);
}

// Round 4
// 203.126 us; speedup vs baseline: 1.4021x; 1.1243x over previous
//
#include <hip/hip_runtime.h>

// B=4, H=W=64, D=256, N=8, K=V=32, H2=W2=32, HW=4096, M=1024 pooled/batch.

typedef _Float16 f16x8 __attribute__((ext_vector_type(8)));
typedef _Float16 f16x4 __attribute__((ext_vector_type(4)));
typedef float    f32x4 __attribute__((ext_vector_type(4)));

#define F16(x) static_cast<_Float16>(x)

// ---------------- prep: weights -> f16 transposed Wt[mat][o][d] -------------
__global__ void prep_kernel(const float* __restrict__ wq, const float* __restrict__ wk,
                            const float* __restrict__ wv, _Float16* __restrict__ wt) {
    int idx = blockIdx.x * 256 + threadIdx.x;     // 196,608 exact
    int mat = idx >> 16;
    int r = idx & 65535;
    int d = r >> 8, o = r & 255;                  // coalesced read along o
    const float* w = (mat == 0) ? wq : (mat == 1 ? wk : wv);
    wt[(mat << 16) + o * 256 + d] = (_Float16)w[d * 256 + o];
}

// ---------------- proj: all three 1x1-conv GEMMs in one launch --------------
// block = 64 rows x 256 cols, 4 waves; wave = 64 rows x 64 cols (4 mc x 4 nt).
// job 0: Q (fused 2x2 maxpool, scale 1/sqrt(32), dst [bn][m][32])   64 blocks
// job 1: K (dst [bn][i][32])                                       256 blocks
// job 2: V (swish, dst [bn][v][4096] == V^T)                       256 blocks
__global__ __launch_bounds__(256) void proj_kernel(
    const float* __restrict__ blob, const _Float16* __restrict__ wt,
    const float* __restrict__ bq, const float* __restrict__ bk, const float* __restrict__ bv,
    _Float16* __restrict__ qo, _Float16* __restrict__ ko, _Float16* __restrict__ vo) {
    const int lane = threadIdx.x & 63, wid = threadIdx.x >> 6;
    const int quad = lane >> 4, l16 = lane & 15;
    int jb = blockIdx.x;
    int job, rowblk;
    if (jb < 64)       { job = 0; rowblk = jb; }
    else if (jb < 320) { job = 1; rowblk = jb - 64; }
    else               { job = 2; rowblk = jb - 320; }
    const int rowbase = rowblk * 64;
    const int colbase = wid * 64;
    const _Float16* wmat = wt + ((size_t)job << 16);
    const float* bias = (job == 0) ? bq : (job == 1 ? bk : bv);

    f32x4 acc[4][4];   // [mc][nt]
#pragma unroll
    for (int mc = 0; mc < 4; ++mc)
#pragma unroll
        for (int nt = 0; nt < 4; ++nt) acc[mc][nt] = (f32x4){0.f, 0.f, 0.f, 0.f};

    const float* a0[4];
#pragma unroll
    for (int mc = 0; mc < 4; ++mc) {
        const int m = rowbase + mc * 16 + l16;
        if (job == 0) {
            const int bb = m >> 10, y = (m >> 5) & 31, x = m & 31;
            a0[mc] = blob + (((bb * 64 + 2 * y) * 64) + 2 * x) * 256;
        } else {
            a0[mc] = blob + (size_t)m * 256;
        }
    }

#pragma unroll 2
    for (int kc = 0; kc < 8; ++kc) {
        f16x8 bf[4];
#pragma unroll
        for (int nt = 0; nt < 4; ++nt)
            bf[nt] = *(const f16x8*)(wmat + (colbase + nt * 16 + l16) * 256 + kc * 32 + quad * 8);
#pragma unroll
        for (int mc = 0; mc < 4; ++mc) {
            const float* ap = a0[mc] + kc * 32 + quad * 8;
            float va[8];
            if (job == 0) {
                float4 p0 = *(const float4*)(ap);
                float4 p1 = *(const float4*)(ap + 4);
                float4 q0 = *(const float4*)(ap + 256);
                float4 q1 = *(const float4*)(ap + 260);
                float4 r0 = *(const float4*)(ap + 16384);
                float4 r1 = *(const float4*)(ap + 16388);
                float4 s0 = *(const float4*)(ap + 16640);
                float4 s1 = *(const float4*)(ap + 16644);
                va[0] = fmaxf(fmaxf(p0.x, q0.x), fmaxf(r0.x, s0.x));
                va[1] = fmaxf(fmaxf(p0.y, q0.y), fmaxf(r0.y, s0.y));
                va[2] = fmaxf(fmaxf(p0.z, q0.z), fmaxf(r0.z, s0.z));
                va[3] = fmaxf(fmaxf(p0.w, q0.w), fmaxf(r0.w, s0.w));
                va[4] = fmaxf(fmaxf(p1.x, q1.x), fmaxf(r1.x, s1.x));
                va[5] = fmaxf(fmaxf(p1.y, q1.y), fmaxf(r1.y, s1.y));
                va[6] = fmaxf(fmaxf(p1.z, q1.z), fmaxf(r1.z, s1.z));
                va[7] = fmaxf(fmaxf(p1.w, q1.w), fmaxf(r1.w, s1.w));
            } else {
                float4 f0 = *(const float4*)(ap);
                float4 f1 = *(const float4*)(ap + 4);
                va[0] = f0.x; va[1] = f0.y; va[2] = f0.z; va[3] = f0.w;
                va[4] = f1.x; va[5] = f1.y; va[6] = f1.z; va[7] = f1.w;
            }
            auto c0 = __builtin_amdgcn_cvt_pkrtz(va[0], va[1]);
            auto c1 = __builtin_amdgcn_cvt_pkrtz(va[2], va[3]);
            auto c2 = __builtin_amdgcn_cvt_pkrtz(va[4], va[5]);
            auto c3 = __builtin_amdgcn_cvt_pkrtz(va[6], va[7]);
            f16x8 af = {F16(c0[0]), F16(c0[1]), F16(c1[0]), F16(c1[1]),
                        F16(c2[0]), F16(c2[1]), F16(c3[0]), F16(c3[1])};
#pragma unroll
            for (int nt = 0; nt < 4; ++nt)
                acc[mc][nt] = __builtin_amdgcn_mfma_f32_16x16x32_f16(af, bf[nt], acc[mc][nt], 0, 0, 0);
        }
    }

#pragma unroll
    for (int nt = 0; nt < 4; ++nt) {
        const int o = colbase + nt * 16 + l16;
        const float bs = bias[o];
        const int nh = o >> 5, kk = o & 31;
#pragma unroll
        for (int mc = 0; mc < 4; ++mc) {
            if (job == 0) {
#pragma unroll
                for (int r = 0; r < 4; ++r) {
                    const int grow = rowbase + mc * 16 + quad * 4 + r;
                    const float x = (acc[mc][nt][r] + bs) * 0.17677669529663687f;
                    const int bb = grow >> 10, mm = grow & 1023;
                    qo[(((bb * 8 + nh) * 1024 + mm) << 5) + kk] = (_Float16)x;
                }
            } else if (job == 1) {
#pragma unroll
                for (int r = 0; r < 4; ++r) {
                    const int grow = rowbase + mc * 16 + quad * 4 + r;
                    const float x = acc[mc][nt][r] + bs;
                    const int bb = grow >> 12, ii = grow & 4095;
                    ko[(((bb * 8 + nh) * 4096 + ii) << 5) + kk] = (_Float16)x;
                }
            } else {
                const int grow0 = rowbase + mc * 16 + quad * 4;
                const int bb = grow0 >> 12, i0 = grow0 & 4095;
                f16x4 pv;
#pragma unroll
                for (int r = 0; r < 4; ++r) {
                    float x = acc[mc][nt][r] + bs;
                    const float sg = 1.0f / (1.0f + __expf(-x));
                    pv[r] = (_Float16)(x * sg);
                }
                *(f16x4*)(vo + (((size_t)(bb * 8 + nh) * 32 + kk) << 12) + i0) = pv;
            }
        }
    }
}

// ---------------- attn: no-max softmax, S^T fragments, 2-stage prefetch -----
// grid: 512 blocks; bn = blockIdx&31 (XCD swizzle: same bn -> same XCD),
// mt = blockIdx>>5. Block = 8 waves (512 thr) covering 64 q-rows; wave wid
// handles keys [wid*512,(wid+1)*512).
__global__ __launch_bounds__(512) void attn_kernel(
    const _Float16* __restrict__ qb,   // [32][1024][32]
    const _Float16* __restrict__ kb,   // [32][4096][32]
    const _Float16* __restrict__ vt,   // [32][32][4096]  (V^T)
    float* __restrict__ out) {         // [4][1024][256]
    __shared__ float cbuf[32][68];     // [v][m] numerator accumulate (pad)
    __shared__ float csum[64];         // denominator per m

    const int tid = threadIdx.x;
    const int lane = tid & 63, wid = tid >> 6;
    const int quad = lane >> 4, l16 = lane & 15;
    const int bn = blockIdx.x & 31, mt = blockIdx.x >> 5;
    const int b = bn >> 3, n = bn & 7;
    const int m0 = mt * 64;

    for (int i = tid; i < 32 * 68; i += 512) ((float*)cbuf)[i] = 0.f;
    if (tid < 64) csum[tid] = 0.f;
    __syncthreads();

    f16x8 qf[4];
#pragma unroll
    for (int mc = 0; mc < 4; ++mc)
        qf[mc] = *(const f16x8*)(qb + (((bn << 10) + m0 + mc * 16 + l16) << 5) + quad * 8);

    const _Float16* kptr = kb + ((size_t)bn << 17) + ((wid << 9) + l16) * 32 + quad * 8;
    const _Float16* vp0  = vt + ((size_t)bn << 17) + l16 * 4096 + (wid << 9) + quad * 4;
    const _Float16* vp1  = vp0 + (16 << 12);

    f32x4 acc[4][2];   // [mc][vc] : out^T[v=vc*16+quad*4+r][m=mc*16+l16]
#pragma unroll
    for (int mc = 0; mc < 4; ++mc) { acc[mc][0] = (f32x4){0.f,0.f,0.f,0.f}; acc[mc][1] = acc[mc][0]; }
    float ps[4] = {0.f, 0.f, 0.f, 0.f};

    // stage 0 preload
    f16x8 kf  = *(const f16x8*)kptr;
    f16x4 va0 = *(const f16x4*)vp0;
    f16x4 va1 = *(const f16x4*)vp1;

    for (int it = 0; it < 32; ++it) {
        kptr += 512; vp0 += 16; vp1 += 16;
        // prefetch next 16-key chunk (last iter over-reads into the adjacent
        // workspace region — ws ordered wt,ko,vo,qo so this is always valid)
        const f16x8 kfn  = *(const f16x8*)kptr;
        const f16x4 va0n = *(const f16x4*)vp0;
        const f16x4 va1n = *(const f16x4*)vp1;

        // S^T tiles: C[i=quad*4+r][m=l16] per m-chunk
        f16x4 pb[4];
#pragma unroll
        for (int mc = 0; mc < 4; ++mc) {
            f32x4 s = __builtin_amdgcn_mfma_f32_16x16x32_f16(kf, qf[mc], (f32x4){0.f,0.f,0.f,0.f}, 0, 0, 0);
            const float p0 = __expf(s[0]), p1 = __expf(s[1]), p2 = __expf(s[2]), p3 = __expf(s[3]);
            ps[mc] += (p0 + p1) + (p2 + p3);
            auto e0 = __builtin_amdgcn_cvt_pkrtz(p0, p1);
            auto e1 = __builtin_amdgcn_cvt_pkrtz(p2, p3);
            pb[mc] = (f16x4){F16(e0[0]), F16(e0[1]), F16(e1[0]), F16(e1[1])};  // B[k=quad*4+j][m=l16]
        }
        // out^T[v][m] += V^T-frag . P^T-frag  (k=16 contraction over keys)
#pragma unroll
        for (int mc = 0; mc < 4; ++mc) {
            acc[mc][0] = __builtin_amdgcn_mfma_f32_16x16x16f16(va0, pb[mc], acc[mc][0], 0, 0, 0);
            acc[mc][1] = __builtin_amdgcn_mfma_f32_16x16x16f16(va1, pb[mc], acc[mc][1], 0, 0, 0);
        }
        kf = kfn; va0 = va0n; va1 = va1n;
    }

    // denominators: reduce across the 4 quads (lane l16 holds m=mc*16+l16)
#pragma unroll
    for (int mc = 0; mc < 4; ++mc) {
        ps[mc] += __shfl_xor(ps[mc], 16);
        ps[mc] += __shfl_xor(ps[mc], 32);
    }

    // block combine: LDS atomic accumulate (8 waves, disjoint key chunks)
#pragma unroll
    for (int mc = 0; mc < 4; ++mc)
#pragma unroll
        for (int vc = 0; vc < 2; ++vc)
#pragma unroll
            for (int r = 0; r < 4; ++r)
                atomicAdd(&cbuf[vc * 16 + quad * 4 + r][mc * 16 + l16], acc[mc][vc][r]);
    if (lane < 16) {
#pragma unroll
        for (int mc = 0; mc < 4; ++mc) atomicAdd(&csum[mc * 16 + l16], ps[mc]);
    }
    __syncthreads();

    // normalize + store: 64 m x 32 v = 2048 outputs, 512 threads x 4
#pragma unroll
    for (int p = 0; p < 4; ++p) {
        const int m = (tid >> 5) + p * 16;
        const int v = tid & 31;
        out[(((b << 10) + m0 + m) << 8) + n * 32 + v] = cbuf[v][m] * (1.0f / csum[m]);
    }
}

// ---------------- launch -----------------------------------------------------
extern "C" void kernel_launch(void* const* d_in, const int* in_sizes, int n_in,
                              void* d_out, int out_size, void* d_ws, size_t ws_size,
                              hipStream_t stream) {
    const float* blob = (const float*)d_in[0];
    const float* wq = (const float*)d_in[1];
    const float* bq = (const float*)d_in[2];
    const float* wk = (const float*)d_in[3];
    const float* bk = (const float*)d_in[4];
    const float* wv = (const float*)d_in[5];
    const float* bv = (const float*)d_in[6];
    float* out = (float*)d_out;

    // Order matters: attn prefetch may over-read <=1 KB past ko/vo; keep qo
    // last so every speculative address stays inside the workspace.
    char* ws = (char*)d_ws;
    _Float16* wt = (_Float16*)(ws);                    //   393,216 B
    _Float16* ko = (_Float16*)(ws + 393216);           // 8,388,608 B
    _Float16* vo = (_Float16*)(ws + 8781824);          // 8,388,608 B
    _Float16* qo = (_Float16*)(ws + 17170432);         // 2,097,152 B

    prep_kernel<<<768, 256, 0, stream>>>(wq, wk, wv, wt);
    proj_kernel<<<576, 256, 0, stream>>>(blob, wt, bq, bk, bv, qo, ko, vo);
    attn_kernel<<<512, 512, 0, stream>>>(qo, ko, vo, out);
}

// Round 5
// 200.295 us; speedup vs baseline: 1.4219x; 1.0141x over previous
//
#include <hip/hip_runtime.h>

// B=4, H=W=64, D=256, N=8, K=V=32, H2=W2=32, HW=4096, M=1024 pooled/batch.

typedef _Float16 f16x8 __attribute__((ext_vector_type(8)));
typedef _Float16 f16x4 __attribute__((ext_vector_type(4)));
typedef float    f32x4 __attribute__((ext_vector_type(4)));

#define F16(x) static_cast<_Float16>(x)

#if __has_builtin(__builtin_amdgcn_exp2f)
#define EXP2(x) __builtin_amdgcn_exp2f(x)
#else
#define EXP2(x) exp2f(x)
#endif

// ---------------- prep: weights -> f16 transposed Wt[mat][o][d] -------------
__global__ void prep_kernel(const float* __restrict__ wq, const float* __restrict__ wk,
                            const float* __restrict__ wv, _Float16* __restrict__ wt) {
    int idx = blockIdx.x * 256 + threadIdx.x;     // 196,608 exact
    int mat = idx >> 16;
    int r = idx & 65535;
    int d = r >> 8, o = r & 255;                  // coalesced read along o
    const float* w = (mat == 0) ? wq : (mat == 1 ? wk : wv);
    wt[(mat << 16) + o * 256 + d] = (_Float16)w[d * 256 + o];
}

// ---------------- proj: all three 1x1-conv GEMMs in one launch --------------
// block = 32 rows x 256 cols, 4 waves; wave = 32 rows x 64 cols (2 mc x 4 nt).
// job 0: Q (fused maxpool, scale log2e/sqrt(32), dst [bn][m][32])  128 blocks
// job 1: K (dst [bn][i][32])                                       512 blocks
// job 2: V (swish, dst [bn][v][4096] == V^T)                       512 blocks
__global__ __launch_bounds__(256) void proj_kernel(
    const float* __restrict__ blob, const _Float16* __restrict__ wt,
    const float* __restrict__ bq, const float* __restrict__ bk, const float* __restrict__ bv,
    _Float16* __restrict__ qo, _Float16* __restrict__ ko, _Float16* __restrict__ vo) {
    const int lane = threadIdx.x & 63, wid = threadIdx.x >> 6;
    const int quad = lane >> 4, l16 = lane & 15;
    int jb = blockIdx.x;
    int job, rowblk;
    if (jb < 128)      { job = 0; rowblk = jb; }
    else if (jb < 640) { job = 1; rowblk = jb - 128; }
    else               { job = 2; rowblk = jb - 640; }
    const int rowbase = rowblk * 32;
    const int colbase = wid * 64;
    const _Float16* wmat = wt + ((size_t)job << 16);
    const float* bias = (job == 0) ? bq : (job == 1 ? bk : bv);

    f32x4 acc[2][4];   // [mc][nt]
#pragma unroll
    for (int mc = 0; mc < 2; ++mc)
#pragma unroll
        for (int nt = 0; nt < 4; ++nt) acc[mc][nt] = (f32x4){0.f, 0.f, 0.f, 0.f};

    const float* a0[2];
#pragma unroll
    for (int mc = 0; mc < 2; ++mc) {
        const int m = rowbase + mc * 16 + l16;
        if (job == 0) {
            const int bb = m >> 10, y = (m >> 5) & 31, x = m & 31;
            a0[mc] = blob + (((bb * 64 + 2 * y) * 64) + 2 * x) * 256;
        } else {
            a0[mc] = blob + (size_t)m * 256;
        }
    }

#pragma unroll 2
    for (int kc = 0; kc < 8; ++kc) {
        f16x8 bf[4];
#pragma unroll
        for (int nt = 0; nt < 4; ++nt)
            bf[nt] = *(const f16x8*)(wmat + (colbase + nt * 16 + l16) * 256 + kc * 32 + quad * 8);
#pragma unroll
        for (int mc = 0; mc < 2; ++mc) {
            const float* ap = a0[mc] + kc * 32 + quad * 8;
            float va[8];
            if (job == 0) {
                float4 p0 = *(const float4*)(ap);
                float4 p1 = *(const float4*)(ap + 4);
                float4 q0 = *(const float4*)(ap + 256);
                float4 q1 = *(const float4*)(ap + 260);
                float4 r0 = *(const float4*)(ap + 16384);
                float4 r1 = *(const float4*)(ap + 16388);
                float4 s0 = *(const float4*)(ap + 16640);
                float4 s1 = *(const float4*)(ap + 16644);
                va[0] = fmaxf(fmaxf(p0.x, q0.x), fmaxf(r0.x, s0.x));
                va[1] = fmaxf(fmaxf(p0.y, q0.y), fmaxf(r0.y, s0.y));
                va[2] = fmaxf(fmaxf(p0.z, q0.z), fmaxf(r0.z, s0.z));
                va[3] = fmaxf(fmaxf(p0.w, q0.w), fmaxf(r0.w, s0.w));
                va[4] = fmaxf(fmaxf(p1.x, q1.x), fmaxf(r1.x, s1.x));
                va[5] = fmaxf(fmaxf(p1.y, q1.y), fmaxf(r1.y, s1.y));
                va[6] = fmaxf(fmaxf(p1.z, q1.z), fmaxf(r1.z, s1.z));
                va[7] = fmaxf(fmaxf(p1.w, q1.w), fmaxf(r1.w, s1.w));
            } else {
                float4 f0 = *(const float4*)(ap);
                float4 f1 = *(const float4*)(ap + 4);
                va[0] = f0.x; va[1] = f0.y; va[2] = f0.z; va[3] = f0.w;
                va[4] = f1.x; va[5] = f1.y; va[6] = f1.z; va[7] = f1.w;
            }
            auto c0 = __builtin_amdgcn_cvt_pkrtz(va[0], va[1]);
            auto c1 = __builtin_amdgcn_cvt_pkrtz(va[2], va[3]);
            auto c2 = __builtin_amdgcn_cvt_pkrtz(va[4], va[5]);
            auto c3 = __builtin_amdgcn_cvt_pkrtz(va[6], va[7]);
            f16x8 af = {F16(c0[0]), F16(c0[1]), F16(c1[0]), F16(c1[1]),
                        F16(c2[0]), F16(c2[1]), F16(c3[0]), F16(c3[1])};
#pragma unroll
            for (int nt = 0; nt < 4; ++nt)
                acc[mc][nt] = __builtin_amdgcn_mfma_f32_16x16x32_f16(af, bf[nt], acc[mc][nt], 0, 0, 0);
        }
    }

#pragma unroll
    for (int nt = 0; nt < 4; ++nt) {
        const int o = colbase + nt * 16 + l16;
        const float bs = bias[o];
        const int nh = o >> 5, kk = o & 31;
#pragma unroll
        for (int mc = 0; mc < 2; ++mc) {
            if (job == 0) {
#pragma unroll
                for (int r = 0; r < 4; ++r) {
                    const int grow = rowbase + mc * 16 + quad * 4 + r;
                    // scale = (1/sqrt(32)) * log2(e): attn uses exp2
                    const float x = (acc[mc][nt][r] + bs) * 0.25503508f;
                    const int bb = grow >> 10, mm = grow & 1023;
                    qo[(((bb * 8 + nh) * 1024 + mm) << 5) + kk] = (_Float16)x;
                }
            } else if (job == 1) {
#pragma unroll
                for (int r = 0; r < 4; ++r) {
                    const int grow = rowbase + mc * 16 + quad * 4 + r;
                    const float x = acc[mc][nt][r] + bs;
                    const int bb = grow >> 12, ii = grow & 4095;
                    ko[(((bb * 8 + nh) * 4096 + ii) << 5) + kk] = (_Float16)x;
                }
            } else {
                const int grow0 = rowbase + mc * 16 + quad * 4;
                const int bb = grow0 >> 12, i0 = grow0 & 4095;
                f16x4 pv;
#pragma unroll
                for (int r = 0; r < 4; ++r) {
                    float x = acc[mc][nt][r] + bs;
                    const float sg = 1.0f / (1.0f + __expf(-x));
                    pv[r] = (_Float16)(x * sg);
                }
                *(f16x4*)(vo + (((size_t)(bb * 8 + nh) * 32 + kk) << 12) + i0) = pv;
            }
        }
    }
}

// ---------------- attn: no-max softmax (exp2), depth-2 pipeline -------------
// grid: 1024 blocks; bn = blockIdx&31 (XCD swizzle), mt = blockIdx>>5.
// Block = 8 waves (512 thr) covering 32 q-rows; wave wid: keys [wid*512,+512).
__global__ __launch_bounds__(512, 6) void attn_kernel(
    const _Float16* __restrict__ qb,   // [32][1024][32]  (pre-scaled by log2e/sqrt32)
    const _Float16* __restrict__ kb,   // [32][4096][32]
    const _Float16* __restrict__ vt,   // [32][32][4096]  (V^T)
    float* __restrict__ out) {         // [4][1024][256]
    __shared__ float cbuf[32][36];     // [v][m] numerator accumulate (pad)
    __shared__ float csum[32];         // denominator per m

    const int tid = threadIdx.x;
    const int lane = tid & 63, wid = tid >> 6;
    const int quad = lane >> 4, l16 = lane & 15;
    const int bn = blockIdx.x & 31, mt = blockIdx.x >> 5;
    const int b = bn >> 3, n = bn & 7;
    const int m0 = mt * 32;

    for (int i = tid; i < 32 * 36; i += 512) ((float*)cbuf)[i] = 0.f;
    if (tid < 32) csum[tid] = 0.f;
    __syncthreads();

    f16x8 qf[2];
    qf[0] = *(const f16x8*)(qb + (((bn << 10) + m0 + l16) << 5) + quad * 8);
    qf[1] = *(const f16x8*)(qb + (((bn << 10) + m0 + 16 + l16) << 5) + quad * 8);

    const _Float16* kptr = kb + ((size_t)bn << 17) + ((wid << 9) + l16) * 32 + quad * 8;
    const _Float16* vp0  = vt + ((size_t)bn << 17) + l16 * 4096 + (wid << 9) + quad * 4;
    const _Float16* vp1  = vp0 + (16 << 12);

    f32x4 acc[2][2];   // [mc][vc] : out^T[v=vc*16+quad*4+r][m=mc*16+l16]
    acc[0][0] = (f32x4){0.f,0.f,0.f,0.f}; acc[0][1] = acc[0][0];
    acc[1][0] = acc[0][0];                 acc[1][1] = acc[0][0];
    float ps[2] = {0.f, 0.f};

    // depth-2 software pipeline, two stages in flight (A = it, B = it+1).
    // Over-reads up to ~2 KB past this bn's K/V region on the final
    // iterations — ws is ordered (wt, ko, vo, qo) so every speculative
    // address stays inside the workspace.
    f16x8 kfA  = *(const f16x8*)kptr;
    f16x4 vaA0 = *(const f16x4*)vp0;
    f16x4 vaA1 = *(const f16x4*)vp1;
    f16x8 kfB  = *(const f16x8*)(kptr + 512);
    f16x4 vaB0 = *(const f16x4*)(vp0 + 16);
    f16x4 vaB1 = *(const f16x4*)(vp1 + 16);

#pragma unroll 1
    for (int it = 0; it < 32; it += 2) {
        kptr += 1024; vp0 += 32; vp1 += 32;
        // prefetch stage it+2
        const f16x8 kfC  = *(const f16x8*)kptr;
        const f16x4 vaC0 = *(const f16x4*)vp0;
        const f16x4 vaC1 = *(const f16x4*)vp1;
        // compute stage A
        {
            f16x4 pb[2];
#pragma unroll
            for (int mc = 0; mc < 2; ++mc) {
                f32x4 s = __builtin_amdgcn_mfma_f32_16x16x32_f16(kfA, qf[mc], (f32x4){0.f,0.f,0.f,0.f}, 0, 0, 0);
                const float p0 = EXP2(s[0]), p1 = EXP2(s[1]), p2 = EXP2(s[2]), p3 = EXP2(s[3]);
                ps[mc] += (p0 + p1) + (p2 + p3);
                auto e0 = __builtin_amdgcn_cvt_pkrtz(p0, p1);
                auto e1 = __builtin_amdgcn_cvt_pkrtz(p2, p3);
                pb[mc] = (f16x4){F16(e0[0]), F16(e0[1]), F16(e1[0]), F16(e1[1])};
            }
#pragma unroll
            for (int mc = 0; mc < 2; ++mc) {
                acc[mc][0] = __builtin_amdgcn_mfma_f32_16x16x16f16(vaA0, pb[mc], acc[mc][0], 0, 0, 0);
                acc[mc][1] = __builtin_amdgcn_mfma_f32_16x16x16f16(vaA1, pb[mc], acc[mc][1], 0, 0, 0);
            }
        }
        // prefetch stage it+3
        const f16x8 kfD  = *(const f16x8*)(kptr + 512);
        const f16x4 vaD0 = *(const f16x4*)(vp0 + 16);
        const f16x4 vaD1 = *(const f16x4*)(vp1 + 16);
        // compute stage B
        {
            f16x4 pb[2];
#pragma unroll
            for (int mc = 0; mc < 2; ++mc) {
                f32x4 s = __builtin_amdgcn_mfma_f32_16x16x32_f16(kfB, qf[mc], (f32x4){0.f,0.f,0.f,0.f}, 0, 0, 0);
                const float p0 = EXP2(s[0]), p1 = EXP2(s[1]), p2 = EXP2(s[2]), p3 = EXP2(s[3]);
                ps[mc] += (p0 + p1) + (p2 + p3);
                auto e0 = __builtin_amdgcn_cvt_pkrtz(p0, p1);
                auto e1 = __builtin_amdgcn_cvt_pkrtz(p2, p3);
                pb[mc] = (f16x4){F16(e0[0]), F16(e0[1]), F16(e1[0]), F16(e1[1])};
            }
#pragma unroll
            for (int mc = 0; mc < 2; ++mc) {
                acc[mc][0] = __builtin_amdgcn_mfma_f32_16x16x16f16(vaB0, pb[mc], acc[mc][0], 0, 0, 0);
                acc[mc][1] = __builtin_amdgcn_mfma_f32_16x16x16f16(vaB1, pb[mc], acc[mc][1], 0, 0, 0);
            }
        }
        kfA = kfC; vaA0 = vaC0; vaA1 = vaC1;
        kfB = kfD; vaB0 = vaD0; vaB1 = vaD1;
    }

    // denominators: reduce across the 4 quads (lane l16 holds m=mc*16+l16)
#pragma unroll
    for (int mc = 0; mc < 2; ++mc) {
        ps[mc] += __shfl_xor(ps[mc], 16);
        ps[mc] += __shfl_xor(ps[mc], 32);
    }

    // block combine: LDS atomic accumulate (8 waves, disjoint key chunks)
#pragma unroll
    for (int mc = 0; mc < 2; ++mc)
#pragma unroll
        for (int vc = 0; vc < 2; ++vc)
#pragma unroll
            for (int r = 0; r < 4; ++r)
                atomicAdd(&cbuf[vc * 16 + quad * 4 + r][mc * 16 + l16], acc[mc][vc][r]);
    if (lane < 16) {
#pragma unroll
        for (int mc = 0; mc < 2; ++mc) atomicAdd(&csum[mc * 16 + l16], ps[mc]);
    }
    __syncthreads();

    // normalize + store: 32 m x 32 v = 1024 outputs, 512 threads x 2
#pragma unroll
    for (int p = 0; p < 2; ++p) {
        const int m = (tid >> 5) + p * 16;
        const int v = tid & 31;
        out[(((b << 10) + m0 + m) << 8) + n * 32 + v] = cbuf[v][m] * (1.0f / csum[m]);
    }
}

// ---------------- launch -----------------------------------------------------
extern "C" void kernel_launch(void* const* d_in, const int* in_sizes, int n_in,
                              void* d_out, int out_size, void* d_ws, size_t ws_size,
                              hipStream_t stream) {
    const float* blob = (const float*)d_in[0];
    const float* wq = (const float*)d_in[1];
    const float* bq = (const float*)d_in[2];
    const float* wk = (const float*)d_in[3];
    const float* bk = (const float*)d_in[4];
    const float* wv = (const float*)d_in[5];
    const float* bv = (const float*)d_in[6];
    float* out = (float*)d_out;

    // Order matters: attn prefetch may over-read ~2 KB past ko/vo; keep qo
    // last so every speculative address stays inside the workspace.
    char* ws = (char*)d_ws;
    _Float16* wt = (_Float16*)(ws);                    //   393,216 B
    _Float16* ko = (_Float16*)(ws + 393216);           // 8,388,608 B
    _Float16* vo = (_Float16*)(ws + 8781824);          // 8,388,608 B
    _Float16* qo = (_Float16*)(ws + 17170432);         // 2,097,152 B

    prep_kernel<<<768, 256, 0, stream>>>(wq, wk, wv, wt);
    proj_kernel<<<1152, 256, 0, stream>>>(blob, wt, bq, bk, bv, qo, ko, vo);
    attn_kernel<<<1024, 512, 0, stream>>>(qo, ko, vo, out);
}

// Round 6
// 168.739 us; speedup vs baseline: 1.6879x; 1.1870x over previous
//
#include <hip/hip_runtime.h>

// B=4, H=W=64, D=256, N=8, K=V=32, H2=W2=32, HW=4096, M=1024 pooled/batch.

typedef _Float16 f16x8 __attribute__((ext_vector_type(8)));
typedef _Float16 f16x4 __attribute__((ext_vector_type(4)));
typedef float    f32x4 __attribute__((ext_vector_type(4)));

#define F16(x) static_cast<_Float16>(x)

#if __has_builtin(__builtin_amdgcn_exp2f)
#define EXP2(x) __builtin_amdgcn_exp2f(x)
#else
#define EXP2(x) exp2f(x)
#endif

// async global->LDS DMA, 16 B per lane; lane i lands at ldsbase + i*16
__device__ __forceinline__ void gl_lds16(const void* g, void* l) {
    __builtin_amdgcn_global_load_lds(
        (const __attribute__((address_space(1))) unsigned int*)g,
        (__attribute__((address_space(3))) unsigned int*)l, 16, 0, 0);
}

// ---------------- prep: weights -> f16 transposed Wt[mat][o][d] -------------
__global__ void prep_kernel(const float* __restrict__ wq, const float* __restrict__ wk,
                            const float* __restrict__ wv, _Float16* __restrict__ wt) {
    int idx = blockIdx.x * 256 + threadIdx.x;     // 196,608 exact
    int mat = idx >> 16;
    int r = idx & 65535;
    int d = r >> 8, o = r & 255;                  // coalesced read along o
    const float* w = (mat == 0) ? wq : (mat == 1 ? wk : wv);
    wt[(mat << 16) + o * 256 + d] = (_Float16)w[d * 256 + o];
}

// ---------------- proj: all three 1x1-conv GEMMs in one launch --------------
// block = 32 rows x 256 cols, 4 waves; wave = 32 rows x 64 cols (2 mc x 4 nt).
__global__ __launch_bounds__(256) void proj_kernel(
    const float* __restrict__ blob, const _Float16* __restrict__ wt,
    const float* __restrict__ bq, const float* __restrict__ bk, const float* __restrict__ bv,
    _Float16* __restrict__ qo, _Float16* __restrict__ ko, _Float16* __restrict__ vo) {
    const int lane = threadIdx.x & 63, wid = threadIdx.x >> 6;
    const int quad = lane >> 4, l16 = lane & 15;
    int jb = blockIdx.x;
    int job, rowblk;
    if (jb < 128)      { job = 0; rowblk = jb; }
    else if (jb < 640) { job = 1; rowblk = jb - 128; }
    else               { job = 2; rowblk = jb - 640; }
    const int rowbase = rowblk * 32;
    const int colbase = wid * 64;
    const _Float16* wmat = wt + ((size_t)job << 16);
    const float* bias = (job == 0) ? bq : (job == 1 ? bk : bv);

    f32x4 acc[2][4];   // [mc][nt]
#pragma unroll
    for (int mc = 0; mc < 2; ++mc)
#pragma unroll
        for (int nt = 0; nt < 4; ++nt) acc[mc][nt] = (f32x4){0.f, 0.f, 0.f, 0.f};

    const float* a0[2];
#pragma unroll
    for (int mc = 0; mc < 2; ++mc) {
        const int m = rowbase + mc * 16 + l16;
        if (job == 0) {
            const int bb = m >> 10, y = (m >> 5) & 31, x = m & 31;
            a0[mc] = blob + (((bb * 64 + 2 * y) * 64) + 2 * x) * 256;
        } else {
            a0[mc] = blob + (size_t)m * 256;
        }
    }

#pragma unroll 2
    for (int kc = 0; kc < 8; ++kc) {
        f16x8 bf[4];
#pragma unroll
        for (int nt = 0; nt < 4; ++nt)
            bf[nt] = *(const f16x8*)(wmat + (colbase + nt * 16 + l16) * 256 + kc * 32 + quad * 8);
#pragma unroll
        for (int mc = 0; mc < 2; ++mc) {
            const float* ap = a0[mc] + kc * 32 + quad * 8;
            float va[8];
            if (job == 0) {
                float4 p0 = *(const float4*)(ap);
                float4 p1 = *(const float4*)(ap + 4);
                float4 q0 = *(const float4*)(ap + 256);
                float4 q1 = *(const float4*)(ap + 260);
                float4 r0 = *(const float4*)(ap + 16384);
                float4 r1 = *(const float4*)(ap + 16388);
                float4 s0 = *(const float4*)(ap + 16640);
                float4 s1 = *(const float4*)(ap + 16644);
                va[0] = fmaxf(fmaxf(p0.x, q0.x), fmaxf(r0.x, s0.x));
                va[1] = fmaxf(fmaxf(p0.y, q0.y), fmaxf(r0.y, s0.y));
                va[2] = fmaxf(fmaxf(p0.z, q0.z), fmaxf(r0.z, s0.z));
                va[3] = fmaxf(fmaxf(p0.w, q0.w), fmaxf(r0.w, s0.w));
                va[4] = fmaxf(fmaxf(p1.x, q1.x), fmaxf(r1.x, s1.x));
                va[5] = fmaxf(fmaxf(p1.y, q1.y), fmaxf(r1.y, s1.y));
                va[6] = fmaxf(fmaxf(p1.z, q1.z), fmaxf(r1.z, s1.z));
                va[7] = fmaxf(fmaxf(p1.w, q1.w), fmaxf(r1.w, s1.w));
            } else {
                float4 f0 = *(const float4*)(ap);
                float4 f1 = *(const float4*)(ap + 4);
                va[0] = f0.x; va[1] = f0.y; va[2] = f0.z; va[3] = f0.w;
                va[4] = f1.x; va[5] = f1.y; va[6] = f1.z; va[7] = f1.w;
            }
            auto c0 = __builtin_amdgcn_cvt_pkrtz(va[0], va[1]);
            auto c1 = __builtin_amdgcn_cvt_pkrtz(va[2], va[3]);
            auto c2 = __builtin_amdgcn_cvt_pkrtz(va[4], va[5]);
            auto c3 = __builtin_amdgcn_cvt_pkrtz(va[6], va[7]);
            f16x8 af = {F16(c0[0]), F16(c0[1]), F16(c1[0]), F16(c1[1]),
                        F16(c2[0]), F16(c2[1]), F16(c3[0]), F16(c3[1])};
#pragma unroll
            for (int nt = 0; nt < 4; ++nt)
                acc[mc][nt] = __builtin_amdgcn_mfma_f32_16x16x32_f16(af, bf[nt], acc[mc][nt], 0, 0, 0);
        }
    }

#pragma unroll
    for (int nt = 0; nt < 4; ++nt) {
        const int o = colbase + nt * 16 + l16;
        const float bs = bias[o];
        const int nh = o >> 5, kk = o & 31;
#pragma unroll
        for (int mc = 0; mc < 2; ++mc) {
            if (job == 0) {
#pragma unroll
                for (int r = 0; r < 4; ++r) {
                    const int grow = rowbase + mc * 16 + quad * 4 + r;
                    // scale = (1/sqrt(32)) * log2(e): attn uses exp2
                    const float x = (acc[mc][nt][r] + bs) * 0.25503508f;
                    const int bb = grow >> 10, mm = grow & 1023;
                    qo[(((bb * 8 + nh) * 1024 + mm) << 5) + kk] = (_Float16)x;
                }
            } else if (job == 1) {
#pragma unroll
                for (int r = 0; r < 4; ++r) {
                    const int grow = rowbase + mc * 16 + quad * 4 + r;
                    const float x = acc[mc][nt][r] + bs;
                    const int bb = grow >> 12, ii = grow & 4095;
                    ko[(((bb * 8 + nh) * 4096 + ii) << 5) + kk] = (_Float16)x;
                }
            } else {
                const int grow0 = rowbase + mc * 16 + quad * 4;
                const int bb = grow0 >> 12, i0 = grow0 & 4095;
                f16x4 pv;
#pragma unroll
                for (int r = 0; r < 4; ++r) {
                    float x = acc[mc][nt][r] + bs;
                    const float sg = 1.0f / (1.0f + __expf(-x));
                    pv[r] = (_Float16)(x * sg);
                }
                *(f16x4*)(vo + (((size_t)(bb * 8 + nh) * 32 + kk) << 12) + i0) = pv;
            }
        }
    }
}

// ---------------- attn: LDS-staged K/V, async DMA double-buffer -------------
// grid 512 = 32 bn (XCD swizzle) x 16 mt; block = 8 waves (512 thr), 64 q-rows.
// wave (rg=wid&1, kc=wid>>1): q-rows [m0+rg*32, +32), keys [kc*1024, +1024).
// 4 K/V streams (one per kc), each double-buffered 64-key tile:
//   stream base kc*16384 + bf*8192: K tile 4 KB | V tile 4 KB.
// K granule (k,c)->k*4+((c+k)&3); V granule (v,c)->v*8+((c+v)&7)  (swizzles
// make ds_read_b128 K-frags and ds_read_b64 V-frags conflict-free; DMA writes
// are lane-contiguous, the swizzle is applied to the SOURCE addresses).
__global__ __launch_bounds__(512, 4) void attn_kernel(
    const _Float16* __restrict__ qb,   // [32][1024][32] (pre-scaled log2e/sqrt32)
    const _Float16* __restrict__ kb,   // [32][4096][32]
    const _Float16* __restrict__ vt,   // [32][32][4096]  (V^T)
    float* __restrict__ out) {         // [4][1024][256]
    __shared__ __align__(16) char pool[65536];

    const int tid = threadIdx.x;
    const int lane = tid & 63, wid = tid >> 6;
    const int quad = lane >> 4, l16 = lane & 15;
    const int bn = blockIdx.x & 31, mt = blockIdx.x >> 5;
    const int b = bn >> 3, n = bn & 7;
    const int m0 = mt * 64;
    const int rg = wid & 1, kc = wid >> 1;

    // ---- per-wave DMA assignments: 4 wave-loads (1 KB each) per step ----
    const _Float16* gsrc[4];
    int ldsoff[4], adv[4];
#pragma unroll
    for (int jj = 0; jj < 4; ++jj) {
        const int j = wid + jj * 8;          // 0..31
        const int kcj = j >> 3, sub = j & 7;
        const int gl = (sub & 3) * 64 + lane;  // granule index in K or V region
        if (sub < 4) {   // K region: invert LG = k*4 + ((c+k)&3)
            const int k = gl >> 2, c = ((gl & 3) - k) & 3;
            gsrc[jj]  = kb + ((size_t)bn << 17) + (kcj * 1024 + k) * 32 + c * 8;
            ldsoff[jj] = kcj * 16384 + gl * 16;
            adv[jj] = 2048;                   // 64 keys * 32 elems per step
        } else {         // V region: invert VG = v*8 + ((c+v)&7)
            const int v = gl >> 3, c = ((gl & 7) - v) & 7;
            gsrc[jj]  = vt + ((size_t)bn << 17) + v * 4096 + kcj * 1024 + c * 8;
            ldsoff[jj] = kcj * 16384 + 4096 + gl * 16;
            adv[jj] = 64;                     // 64 keys per step
        }
    }

    // Q fragments (L2-hot)
    f16x8 qf[2];
#pragma unroll
    for (int mc = 0; mc < 2; ++mc)
        qf[mc] = *(const f16x8*)(qb + (((bn << 10) + m0 + rg * 32 + mc * 16 + l16) << 5) + quad * 8);

    // prologue: DMA step 0 into buffer 0
#pragma unroll
    for (int jj = 0; jj < 4; ++jj) {
        gl_lds16(gsrc[jj], pool + ldsoff[jj]);
        gsrc[jj] += adv[jj];
    }

    f32x4 acc[2][2];   // [mc][vc]: out^T[v=vc*16+quad*4+r][m=rg*32+mc*16+l16]
    acc[0][0] = (f32x4){0.f,0.f,0.f,0.f}; acc[0][1] = acc[0][0];
    acc[1][0] = acc[0][0];                 acc[1][1] = acc[0][0];
    float ps0 = 0.f, ps1 = 0.f;

    // per-lane read bases
    const int kread = kc * 16384 + l16 * 64 + ((quad + l16) & 3) * 16;
    const int vread = kc * 16384 + 4096 + l16 * 128 + (quad & 1) * 8;
    const int r0 = (quad >> 1) + l16;

    asm volatile("s_waitcnt vmcnt(0)" ::: "memory");
    __syncthreads();

    for (int s = 0; s < 16; ++s) {
        const int bf = (s & 1) * 8192;
        if (s < 15) {   // DMA step s+1 into the other buffer
            const int nb = ((s + 1) & 1) * 8192;
#pragma unroll
            for (int jj = 0; jj < 4; ++jj) {
                gl_lds16(gsrc[jj], pool + ldsoff[jj] + nb);
                gsrc[jj] += adv[jj];
            }
        }
        const char* kbase = pool + kread + bf;
        const char* vbase = pool + vread + bf;
#pragma unroll
        for (int tloc = 0; tloc < 4; ++tloc) {
            const f16x8 kf = *(const f16x8*)(kbase + tloc * 1024);
            const int rot = ((2 * tloc + r0) & 7) * 16;
            const f16x4 va0 = *(const f16x4*)(vbase + rot);
            const f16x4 va1 = *(const f16x4*)(vbase + rot + 2048);

            f32x4 s0 = __builtin_amdgcn_mfma_f32_16x16x32_f16(kf, qf[0], (f32x4){0.f,0.f,0.f,0.f}, 0, 0, 0);
            f32x4 s1 = __builtin_amdgcn_mfma_f32_16x16x32_f16(kf, qf[1], (f32x4){0.f,0.f,0.f,0.f}, 0, 0, 0);
            const float p0 = EXP2(s0[0]), p1 = EXP2(s0[1]), p2 = EXP2(s0[2]), p3 = EXP2(s0[3]);
            const float u0 = EXP2(s1[0]), u1 = EXP2(s1[1]), u2 = EXP2(s1[2]), u3 = EXP2(s1[3]);
            ps0 += (p0 + p1) + (p2 + p3);
            ps1 += (u0 + u1) + (u2 + u3);
            auto e0 = __builtin_amdgcn_cvt_pkrtz(p0, p1);
            auto e1 = __builtin_amdgcn_cvt_pkrtz(p2, p3);
            auto e2 = __builtin_amdgcn_cvt_pkrtz(u0, u1);
            auto e3 = __builtin_amdgcn_cvt_pkrtz(u2, u3);
            const f16x4 pb0 = {F16(e0[0]), F16(e0[1]), F16(e1[0]), F16(e1[1])};
            const f16x4 pb1 = {F16(e2[0]), F16(e2[1]), F16(e3[0]), F16(e3[1])};
            acc[0][0] = __builtin_amdgcn_mfma_f32_16x16x16f16(va0, pb0, acc[0][0], 0, 0, 0);
            acc[0][1] = __builtin_amdgcn_mfma_f32_16x16x16f16(va1, pb0, acc[0][1], 0, 0, 0);
            acc[1][0] = __builtin_amdgcn_mfma_f32_16x16x16f16(va0, pb1, acc[1][0], 0, 0, 0);
            acc[1][1] = __builtin_amdgcn_mfma_f32_16x16x16f16(va1, pb1, acc[1][1], 0, 0, 0);
        }
        asm volatile("s_waitcnt vmcnt(0)" ::: "memory");
        __syncthreads();
    }

    // ---- epilogue: 4-way key-split combine in (now free) LDS ----
    float* num = (float*)pool;                 // [64][33]
    float* den = (float*)(pool + 64 * 33 * 4); // [64]
    for (int i = tid; i < 64 * 33 + 64; i += 512) ((float*)pool)[i] = 0.f;
    __syncthreads();

    ps0 += __shfl_xor(ps0, 16); ps0 += __shfl_xor(ps0, 32);
    ps1 += __shfl_xor(ps1, 16); ps1 += __shfl_xor(ps1, 32);

#pragma unroll
    for (int mc = 0; mc < 2; ++mc) {
        const int m = rg * 32 + mc * 16 + l16;
#pragma unroll
        for (int vc = 0; vc < 2; ++vc)
#pragma unroll
            for (int r = 0; r < 4; ++r)
                atomicAdd(&num[m * 33 + vc * 16 + quad * 4 + r], acc[mc][vc][r]);
    }
    if (quad == 0) {
        atomicAdd(&den[rg * 32 + l16], ps0);
        atomicAdd(&den[rg * 32 + 16 + l16], ps1);
    }
    __syncthreads();

    // store: 64 m x 32 v = 2048 f32 = 512 threads x one float4
    {
        const int mloc = tid >> 3, v4 = (tid & 7) * 4;
        const float inv = 1.0f / den[mloc];
        const float* nr = num + mloc * 33 + v4;
        float4 o = {nr[0] * inv, nr[1] * inv, nr[2] * inv, nr[3] * inv};
        *(float4*)(out + (((b << 10) + m0 + mloc) << 8) + n * 32 + v4) = o;
    }
}

// ---------------- launch -----------------------------------------------------
extern "C" void kernel_launch(void* const* d_in, const int* in_sizes, int n_in,
                              void* d_out, int out_size, void* d_ws, size_t ws_size,
                              hipStream_t stream) {
    const float* blob = (const float*)d_in[0];
    const float* wq = (const float*)d_in[1];
    const float* bq = (const float*)d_in[2];
    const float* wk = (const float*)d_in[3];
    const float* bk = (const float*)d_in[4];
    const float* wv = (const float*)d_in[5];
    const float* bv = (const float*)d_in[6];
    float* out = (float*)d_out;

    char* ws = (char*)d_ws;
    _Float16* wt = (_Float16*)(ws);                    //   393,216 B
    _Float16* ko = (_Float16*)(ws + 393216);           // 8,388,608 B
    _Float16* vo = (_Float16*)(ws + 8781824);          // 8,388,608 B
    _Float16* qo = (_Float16*)(ws + 17170432);         // 2,097,152 B

    prep_kernel<<<768, 256, 0, stream>>>(wq, wk, wv, wt);
    proj_kernel<<<1152, 256, 0, stream>>>(blob, wt, bq, bk, bv, qo, ko, vo);
    attn_kernel<<<512, 512, 0, stream>>>(qo, ko, vo, out);
}

// Round 7
// 167.373 us; speedup vs baseline: 1.7016x; 1.0082x over previous
//
#include <hip/hip_runtime.h>

// B=4, H=W=64, D=256, N=8, K=V=32, H2=W2=32, HW=4096, M=1024 pooled/batch.

typedef _Float16 f16x8 __attribute__((ext_vector_type(8)));
typedef _Float16 f16x4 __attribute__((ext_vector_type(4)));
typedef float    f32x4 __attribute__((ext_vector_type(4)));

#define F16(x) static_cast<_Float16>(x)

#if __has_builtin(__builtin_amdgcn_exp2f)
#define EXP2(x) __builtin_amdgcn_exp2f(x)
#else
#define EXP2(x) exp2f(x)
#endif

// async global->LDS DMA, 16 B per lane; lane i lands at ldsbase + i*16
__device__ __forceinline__ void gl_lds16(const void* g, void* l) {
    __builtin_amdgcn_global_load_lds(
        (const __attribute__((address_space(1))) unsigned int*)g,
        (__attribute__((address_space(3))) unsigned int*)l, 16, 0, 0);
}

// ---------------- prep: weights -> f16 transposed Wt[mat][o][d] -------------
__global__ void prep_kernel(const float* __restrict__ wq, const float* __restrict__ wk,
                            const float* __restrict__ wv, _Float16* __restrict__ wt) {
    int idx = blockIdx.x * 256 + threadIdx.x;     // 196,608 exact
    int mat = idx >> 16;
    int r = idx & 65535;
    int d = r >> 8, o = r & 255;                  // coalesced read along o
    const float* w = (mat == 0) ? wq : (mat == 1 ? wk : wv);
    wt[(mat << 16) + o * 256 + d] = (_Float16)w[d * 256 + o];
}

// ---------------- proj: all three 1x1-conv GEMMs in one launch --------------
// block = 32 rows x 256 cols, 4 waves; wave = 32 rows x 64 cols (2 mc x 4 nt).
__global__ __launch_bounds__(256) void proj_kernel(
    const float* __restrict__ blob, const _Float16* __restrict__ wt,
    const float* __restrict__ bq, const float* __restrict__ bk, const float* __restrict__ bv,
    _Float16* __restrict__ qo, _Float16* __restrict__ ko, _Float16* __restrict__ vo) {
    const int lane = threadIdx.x & 63, wid = threadIdx.x >> 6;
    const int quad = lane >> 4, l16 = lane & 15;
    int jb = blockIdx.x;
    int job, rowblk;
    if (jb < 128)      { job = 0; rowblk = jb; }
    else if (jb < 640) { job = 1; rowblk = jb - 128; }
    else               { job = 2; rowblk = jb - 640; }
    const int rowbase = rowblk * 32;
    const int colbase = wid * 64;
    const _Float16* wmat = wt + ((size_t)job << 16);
    const float* bias = (job == 0) ? bq : (job == 1 ? bk : bv);

    f32x4 acc[2][4];   // [mc][nt]
#pragma unroll
    for (int mc = 0; mc < 2; ++mc)
#pragma unroll
        for (int nt = 0; nt < 4; ++nt) acc[mc][nt] = (f32x4){0.f, 0.f, 0.f, 0.f};

    const float* a0[2];
#pragma unroll
    for (int mc = 0; mc < 2; ++mc) {
        const int m = rowbase + mc * 16 + l16;
        if (job == 0) {
            const int bb = m >> 10, y = (m >> 5) & 31, x = m & 31;
            a0[mc] = blob + (((bb * 64 + 2 * y) * 64) + 2 * x) * 256;
        } else {
            a0[mc] = blob + (size_t)m * 256;
        }
    }

#pragma unroll 2
    for (int kc = 0; kc < 8; ++kc) {
        f16x8 bf[4];
#pragma unroll
        for (int nt = 0; nt < 4; ++nt)
            bf[nt] = *(const f16x8*)(wmat + (colbase + nt * 16 + l16) * 256 + kc * 32 + quad * 8);
#pragma unroll
        for (int mc = 0; mc < 2; ++mc) {
            const float* ap = a0[mc] + kc * 32 + quad * 8;
            float va[8];
            if (job == 0) {
                float4 p0 = *(const float4*)(ap);
                float4 p1 = *(const float4*)(ap + 4);
                float4 q0 = *(const float4*)(ap + 256);
                float4 q1 = *(const float4*)(ap + 260);
                float4 r0 = *(const float4*)(ap + 16384);
                float4 r1 = *(const float4*)(ap + 16388);
                float4 s0 = *(const float4*)(ap + 16640);
                float4 s1 = *(const float4*)(ap + 16644);
                va[0] = fmaxf(fmaxf(p0.x, q0.x), fmaxf(r0.x, s0.x));
                va[1] = fmaxf(fmaxf(p0.y, q0.y), fmaxf(r0.y, s0.y));
                va[2] = fmaxf(fmaxf(p0.z, q0.z), fmaxf(r0.z, s0.z));
                va[3] = fmaxf(fmaxf(p0.w, q0.w), fmaxf(r0.w, s0.w));
                va[4] = fmaxf(fmaxf(p1.x, q1.x), fmaxf(r1.x, s1.x));
                va[5] = fmaxf(fmaxf(p1.y, q1.y), fmaxf(r1.y, s1.y));
                va[6] = fmaxf(fmaxf(p1.z, q1.z), fmaxf(r1.z, s1.z));
                va[7] = fmaxf(fmaxf(p1.w, q1.w), fmaxf(r1.w, s1.w));
            } else {
                float4 f0 = *(const float4*)(ap);
                float4 f1 = *(const float4*)(ap + 4);
                va[0] = f0.x; va[1] = f0.y; va[2] = f0.z; va[3] = f0.w;
                va[4] = f1.x; va[5] = f1.y; va[6] = f1.z; va[7] = f1.w;
            }
            auto c0 = __builtin_amdgcn_cvt_pkrtz(va[0], va[1]);
            auto c1 = __builtin_amdgcn_cvt_pkrtz(va[2], va[3]);
            auto c2 = __builtin_amdgcn_cvt_pkrtz(va[4], va[5]);
            auto c3 = __builtin_amdgcn_cvt_pkrtz(va[6], va[7]);
            f16x8 af = {F16(c0[0]), F16(c0[1]), F16(c1[0]), F16(c1[1]),
                        F16(c2[0]), F16(c2[1]), F16(c3[0]), F16(c3[1])};
#pragma unroll
            for (int nt = 0; nt < 4; ++nt)
                acc[mc][nt] = __builtin_amdgcn_mfma_f32_16x16x32_f16(af, bf[nt], acc[mc][nt], 0, 0, 0);
        }
    }

#pragma unroll
    for (int nt = 0; nt < 4; ++nt) {
        const int o = colbase + nt * 16 + l16;
        const float bs = bias[o];
        const int nh = o >> 5, kk = o & 31;
#pragma unroll
        for (int mc = 0; mc < 2; ++mc) {
            if (job == 0) {
#pragma unroll
                for (int r = 0; r < 4; ++r) {
                    const int grow = rowbase + mc * 16 + quad * 4 + r;
                    // scale = (1/sqrt(32)) * log2(e): attn uses exp2
                    const float x = (acc[mc][nt][r] + bs) * 0.25503508f;
                    const int bb = grow >> 10, mm = grow & 1023;
                    qo[(((bb * 8 + nh) * 1024 + mm) << 5) + kk] = (_Float16)x;
                }
            } else if (job == 1) {
#pragma unroll
                for (int r = 0; r < 4; ++r) {
                    const int grow = rowbase + mc * 16 + quad * 4 + r;
                    const float x = acc[mc][nt][r] + bs;
                    const int bb = grow >> 12, ii = grow & 4095;
                    ko[(((bb * 8 + nh) * 4096 + ii) << 5) + kk] = (_Float16)x;
                }
            } else {
                const int grow0 = rowbase + mc * 16 + quad * 4;
                const int bb = grow0 >> 12, i0 = grow0 & 4095;
                f16x4 pv;
#pragma unroll
                for (int r = 0; r < 4; ++r) {
                    float x = acc[mc][nt][r] + bs;
                    const float sg = 1.0f / (1.0f + __expf(-x));
                    pv[r] = (_Float16)(x * sg);
                }
                *(f16x4*)(vo + (((size_t)(bb * 8 + nh) * 32 + kk) << 12) + i0) = pv;
            }
        }
    }
}

// ---------------- attn: LDS-staged K/V, async DMA double-buffer -------------
// grid 512 = 32 bn (XCD swizzle) x 16 mt; block = 8 waves (512 thr), 64 q-rows.
// wave (rg=wid&1, kc=wid>>1): q-rows [m0+rg*32, +32), keys [kc*1024, +1024).
// 4 K/V streams (one per kc), each double-buffered 64-key tile:
//   stream base kc*16384 + bf*8192: K tile 4 KB | V tile 4 KB.
// K granule (k,c) -> slot k*4 + ((c + (k>>2))&3): for a fixed read phase
// (quad), slot%8 = (l16&1)*4 + ((quad+(l16>>2))&3) sweeps all 8 bank-quads
// exactly 2x -> conflict-free ds_read_b128 (the old (c+k)&3 swizzle only hit
// 2 of 4 windows per parity -> 4-way conflicts, 3.1M counter in round 6).
// V granule (v,c) -> v*8 + ((c+v)&7): conflict-free for the b64 reads.
__global__ __launch_bounds__(512, 4) void attn_kernel(
    const _Float16* __restrict__ qb,   // [32][1024][32] (pre-scaled log2e/sqrt32)
    const _Float16* __restrict__ kb,   // [32][4096][32]
    const _Float16* __restrict__ vt,   // [32][32][4096]  (V^T)
    float* __restrict__ out) {         // [4][1024][256]
    __shared__ __align__(16) char pool[65536];

    const int tid = threadIdx.x;
    const int lane = tid & 63, wid = tid >> 6;
    const int quad = lane >> 4, l16 = lane & 15;
    const int bn = blockIdx.x & 31, mt = blockIdx.x >> 5;
    const int b = bn >> 3, n = bn & 7;
    const int m0 = mt * 64;
    const int rg = wid & 1, kc = wid >> 1;

    // ---- per-wave DMA assignments: 4 wave-loads (1 KB each) per step ----
    const _Float16* gsrc[4];
    int ldsoff[4], adv[4];
#pragma unroll
    for (int jj = 0; jj < 4; ++jj) {
        const int j = wid + jj * 8;          // 0..31
        const int kcj = j >> 3, sub = j & 7;
        const int gl = (sub & 3) * 64 + lane;  // granule slot in K or V region
        if (sub < 4) {   // K region: invert slot = k*4 + ((c + (k>>2))&3)
            const int k = gl >> 2, c = ((gl & 3) - (k >> 2)) & 3;
            gsrc[jj]  = kb + ((size_t)bn << 17) + (kcj * 1024 + k) * 32 + c * 8;
            ldsoff[jj] = kcj * 16384 + gl * 16;
            adv[jj] = 2048;                   // 64 keys * 32 elems per step
        } else {         // V region: invert slot = v*8 + ((c+v)&7)
            const int v = gl >> 3, c = ((gl & 7) - v) & 7;
            gsrc[jj]  = vt + ((size_t)bn << 17) + v * 4096 + kcj * 1024 + c * 8;
            ldsoff[jj] = kcj * 16384 + 4096 + gl * 16;
            adv[jj] = 64;                     // 64 keys per step
        }
    }

    // Q fragments (L2-hot)
    f16x8 qf[2];
#pragma unroll
    for (int mc = 0; mc < 2; ++mc)
        qf[mc] = *(const f16x8*)(qb + (((bn << 10) + m0 + rg * 32 + mc * 16 + l16) << 5) + quad * 8);

    // prologue: DMA step 0 into buffer 0
#pragma unroll
    for (int jj = 0; jj < 4; ++jj) {
        gl_lds16(gsrc[jj], pool + ldsoff[jj]);
        gsrc[jj] += adv[jj];
    }

    f32x4 acc[2][2];   // [mc][vc]: out^T[v=vc*16+quad*4+r][m=rg*32+mc*16+l16]
    acc[0][0] = (f32x4){0.f,0.f,0.f,0.f}; acc[0][1] = acc[0][0];
    acc[1][0] = acc[0][0];                 acc[1][1] = acc[0][0];
    float ps0 = 0.f, ps1 = 0.f;

    // per-lane read bases (K read offset is tloc-invariant by construction)
    const int kread = kc * 16384 + l16 * 64 + ((quad + (l16 >> 2)) & 3) * 16;
    const int vread = kc * 16384 + 4096 + l16 * 128 + (quad & 1) * 8;
    const int r0 = (quad >> 1) + l16;

    asm volatile("s_waitcnt vmcnt(0)" ::: "memory");
    __syncthreads();

    for (int s = 0; s < 16; ++s) {
        const int bf = (s & 1) * 8192;
        if (s < 15) {   // DMA step s+1 into the other buffer
            const int nb = ((s + 1) & 1) * 8192;
#pragma unroll
            for (int jj = 0; jj < 4; ++jj) {
                gl_lds16(gsrc[jj], pool + ldsoff[jj] + nb);
                gsrc[jj] += adv[jj];
            }
        }
        const char* kbase = pool + kread + bf;
        const char* vbase = pool + vread + bf;
#pragma unroll
        for (int tloc = 0; tloc < 4; ++tloc) {
            const f16x8 kf = *(const f16x8*)(kbase + tloc * 1024);
            const int rot = ((2 * tloc + r0) & 7) * 16;
            const f16x4 va0 = *(const f16x4*)(vbase + rot);
            const f16x4 va1 = *(const f16x4*)(vbase + rot + 2048);

            f32x4 s0 = __builtin_amdgcn_mfma_f32_16x16x32_f16(kf, qf[0], (f32x4){0.f,0.f,0.f,0.f}, 0, 0, 0);
            f32x4 s1 = __builtin_amdgcn_mfma_f32_16x16x32_f16(kf, qf[1], (f32x4){0.f,0.f,0.f,0.f}, 0, 0, 0);
            const float p0 = EXP2(s0[0]), p1 = EXP2(s0[1]), p2 = EXP2(s0[2]), p3 = EXP2(s0[3]);
            const float u0 = EXP2(s1[0]), u1 = EXP2(s1[1]), u2 = EXP2(s1[2]), u3 = EXP2(s1[3]);
            ps0 += (p0 + p1) + (p2 + p3);
            ps1 += (u0 + u1) + (u2 + u3);
            auto e0 = __builtin_amdgcn_cvt_pkrtz(p0, p1);
            auto e1 = __builtin_amdgcn_cvt_pkrtz(p2, p3);
            auto e2 = __builtin_amdgcn_cvt_pkrtz(u0, u1);
            auto e3 = __builtin_amdgcn_cvt_pkrtz(u2, u3);
            const f16x4 pb0 = {F16(e0[0]), F16(e0[1]), F16(e1[0]), F16(e1[1])};
            const f16x4 pb1 = {F16(e2[0]), F16(e2[1]), F16(e3[0]), F16(e3[1])};
            acc[0][0] = __builtin_amdgcn_mfma_f32_16x16x16f16(va0, pb0, acc[0][0], 0, 0, 0);
            acc[0][1] = __builtin_amdgcn_mfma_f32_16x16x16f16(va1, pb0, acc[0][1], 0, 0, 0);
            acc[1][0] = __builtin_amdgcn_mfma_f32_16x16x16f16(va0, pb1, acc[1][0], 0, 0, 0);
            acc[1][1] = __builtin_amdgcn_mfma_f32_16x16x16f16(va1, pb1, acc[1][1], 0, 0, 0);
        }
        asm volatile("s_waitcnt vmcnt(0)" ::: "memory");
        __syncthreads();
    }

    // ---- epilogue: 4-way key-split combine in (now free) LDS ----
    float* num = (float*)pool;                 // [64][33]
    float* den = (float*)(pool + 64 * 33 * 4); // [64]
    for (int i = tid; i < 64 * 33 + 64; i += 512) ((float*)pool)[i] = 0.f;
    __syncthreads();

    ps0 += __shfl_xor(ps0, 16); ps0 += __shfl_xor(ps0, 32);
    ps1 += __shfl_xor(ps1, 16); ps1 += __shfl_xor(ps1, 32);

#pragma unroll
    for (int mc = 0; mc < 2; ++mc) {
        const int m = rg * 32 + mc * 16 + l16;
#pragma unroll
        for (int vc = 0; vc < 2; ++vc)
#pragma unroll
            for (int r = 0; r < 4; ++r)
                atomicAdd(&num[m * 33 + vc * 16 + quad * 4 + r], acc[mc][vc][r]);
    }
    if (quad == 0) {
        atomicAdd(&den[rg * 32 + l16], ps0);
        atomicAdd(&den[rg * 32 + 16 + l16], ps1);
    }
    __syncthreads();

    // store: 64 m x 32 v = 2048 f32 = 512 threads x one float4
    {
        const int mloc = tid >> 3, v4 = (tid & 7) * 4;
        const float inv = 1.0f / den[mloc];
        const float* nr = num + mloc * 33 + v4;
        float4 o = {nr[0] * inv, nr[1] * inv, nr[2] * inv, nr[3] * inv};
        *(float4*)(out + (((b << 10) + m0 + mloc) << 8) + n * 32 + v4) = o;
    }
}

// ---------------- launch -----------------------------------------------------
extern "C" void kernel_launch(void* const* d_in, const int* in_sizes, int n_in,
                              void* d_out, int out_size, void* d_ws, size_t ws_size,
                              hipStream_t stream) {
    const float* blob = (const float*)d_in[0];
    const float* wq = (const float*)d_in[1];
    const float* bq = (const float*)d_in[2];
    const float* wk = (const float*)d_in[3];
    const float* bk = (const float*)d_in[4];
    const float* wv = (const float*)d_in[5];
    const float* bv = (const float*)d_in[6];
    float* out = (float*)d_out;

    char* ws = (char*)d_ws;
    _Float16* wt = (_Float16*)(ws);                    //   393,216 B
    _Float16* ko = (_Float16*)(ws + 393216);           // 8,388,608 B
    _Float16* vo = (_Float16*)(ws + 8781824);          // 8,388,608 B
    _Float16* qo = (_Float16*)(ws + 17170432);         // 2,097,152 B

    prep_kernel<<<768, 256, 0, stream>>>(wq, wk, wv, wt);
    proj_kernel<<<1152, 256, 0, stream>>>(blob, wt, bq, bk, bv, qo, ko, vo);
    attn_kernel<<<512, 512, 0, stream>>>(qo, ko, vo, out);
}